// Round 1
// baseline (192.933 us; speedup 1.0000x reference)
//
#include <hip/hip_runtime.h>
#include <math.h>

#define NN 6144
#define DD 512
#define CAP 128

typedef __bf16 bf16_t;
typedef __bf16 bf16x8 __attribute__((ext_vector_type(8)));
typedef float f32x4 __attribute__((ext_vector_type(4)));

__device__ __forceinline__ float bf2f(unsigned short u) {
    unsigned v = ((unsigned)u) << 16;
    return __builtin_bit_cast(float, v);
}
__device__ __forceinline__ unsigned short f2bf(float f) {
    unsigned u = __builtin_bit_cast(unsigned, f);
    u += 0x7fffu + ((u >> 16) & 1u);   // round-to-nearest-even
    return (unsigned short)(u >> 16);
}
__device__ __forceinline__ float sigmoidf_(float z) { return 1.0f / (1.0f + expf(-z)); }

// ---------------- kernel 1a: x (f32) -> xb (bf16) ----------------
__global__ void k_conv_x(const float* __restrict__ x, unsigned short* __restrict__ xb) {
    int i = (blockIdx.x * blockDim.x + threadIdx.x) * 4;
    float4 v = *(const float4*)(x + i);
    ushort4 o;
    o.x = f2bf(v.x); o.y = f2bf(v.y); o.z = f2bf(v.z); o.w = f2bf(v.w);
    *(ushort4*)(xb + i) = o;
}

// ---------------- kernel 1b: Wt[n][k] = [W_sa | W_gcnb]^T in bf16 ----------------
__global__ void k_conv_w(const float* __restrict__ Wsa, const float* __restrict__ Wg,
                         unsigned short* __restrict__ wt) {
    int id = blockIdx.x * blockDim.x + threadIdx.x;   // id = n*512 + k
    int n = id >> 9, k = id & 511;
    float v = (n < 512) ? Wsa[k * 512 + n] : Wg[k * 512 + (n - 512)];
    wt[id] = f2bf(v);
}

// ---------------- kernel 2: per-row gate projections ----------------
__global__ void k_proj(const float* __restrict__ x, const float* __restrict__ Wa,
                       const float* __restrict__ Wb,
                       float* __restrict__ xal, float* __restrict__ xar,
                       float* __restrict__ xbl, float* __restrict__ xbr) {
    int wave = threadIdx.x >> 6, lane = threadIdx.x & 63;
    int row = blockIdx.x * 4 + wave;
    int k0 = lane * 8;
    const float* xr_ = x + (size_t)row * DD + k0;
    float4 v0 = *(const float4*)xr_;
    float4 v1 = *(const float4*)(xr_ + 4);
    float a0 = 0, a1 = 0, b0 = 0, b1 = 0;
    float xv[8] = {v0.x, v0.y, v0.z, v0.w, v1.x, v1.y, v1.z, v1.w};
#pragma unroll
    for (int j = 0; j < 8; j++) {
        a0 += xv[j] * Wa[k0 + j];
        a1 += xv[j] * Wa[512 + k0 + j];
        b0 += xv[j] * Wb[k0 + j];
        b1 += xv[j] * Wb[512 + k0 + j];
    }
#pragma unroll
    for (int off = 32; off; off >>= 1) {
        a0 += __shfl_down(a0, off); a1 += __shfl_down(a1, off);
        b0 += __shfl_down(b0, off); b1 += __shfl_down(b1, off);
    }
    if (lane == 0) { xal[row] = a0; xar[row] = a1; xbl[row] = b0; xbr[row] = b1; }
}

// ---------------- kernel 3: sparsify adjacency + fused gate ----------------
__global__ void k_sparsify(const float* __restrict__ adjA, const float* __restrict__ adjB,
                           const float* __restrict__ xal, const float* __restrict__ xar,
                           const float* __restrict__ xbl, const float* __restrict__ xbr,
                           const float* __restrict__ ba, const float* __restrict__ bb,
                           int* __restrict__ idxA, int* __restrict__ idxB,
                           int* __restrict__ cntA, int* __restrict__ cntB,
                           float* __restrict__ gateA, float* __restrict__ gateB) {
    int row = blockIdx.x;
    int which = blockIdx.y;           // 0 -> A, 1 -> B
    const float* adj = which ? adjB : adjA;
    const float* xl = which ? xbl : xal;
    int* idx = which ? idxB : idxA;

    __shared__ int s_cnt;
    __shared__ float s_part[4];
    if (threadIdx.x == 0) s_cnt = 0;
    __syncthreads();

    const float4* arow = (const float4*)(adj + (size_t)row * NN);
    float gsum = 0.f;
    for (int i = threadIdx.x; i < NN / 4; i += 256) {
        float4 v = arow[i];
        float f[4] = {v.x, v.y, v.z, v.w};
#pragma unroll
        for (int c = 0; c < 4; c++) {
            if (f[c] != 0.0f) {
                int p = atomicAdd(&s_cnt, 1);
                if (p < CAP) idx[(size_t)row * CAP + p] = i * 4 + c;
                gsum += xl[i * 4 + c];
            }
        }
    }
#pragma unroll
    for (int off = 32; off; off >>= 1) gsum += __shfl_down(gsum, off);
    int lane = threadIdx.x & 63, wave = threadIdx.x >> 6;
    if (lane == 0) s_part[wave] = gsum;
    __syncthreads();
    if (threadIdx.x == 0) {
        int c = s_cnt; if (c > CAP) c = CAP;
        (which ? cntB : cntA)[row] = c;
        float tot = s_part[0] + s_part[1] + s_part[2] + s_part[3];
        float z = tot + (which ? xbr : xar)[row] + (which ? bb : ba)[0];
        (which ? gateB : gateA)[row] = sigmoidf_(z);
    }
}

// ---------------- kernel 4: bf16 MFMA GEMM  C = xb @ [W_sa | W_gcnb] ----------------
// grid (96,16), block 256 (4 waves). Each wave: 16x64 tile via 4 acc fragments.
__global__ __launch_bounds__(256) void k_gemm(const bf16_t* __restrict__ xb,
                                              const bf16_t* __restrict__ wt,
                                              unsigned short* __restrict__ h,
                                              unsigned short* __restrict__ g) {
    int wave = threadIdx.x >> 6, lane = threadIdx.x & 63;
    int row0 = blockIdx.x * 64 + wave * 16;
    int col0 = blockIdx.y * 64;
    int lr = lane & 15;
    int kg = (lane >> 4) * 8;

    f32x4 acc[4] = {{0, 0, 0, 0}, {0, 0, 0, 0}, {0, 0, 0, 0}, {0, 0, 0, 0}};
    const bf16_t* ap = xb + (size_t)(row0 + lr) * DD + kg;
    const bf16_t* bp = wt + (size_t)(col0 + lr) * DD + kg;

    for (int k0 = 0; k0 < DD; k0 += 32) {
        bf16x8 a = *(const bf16x8*)(ap + k0);
#pragma unroll
        for (int n = 0; n < 4; n++) {
            bf16x8 b = *(const bf16x8*)(bp + (size_t)n * 16 * DD + k0);
            acc[n] = __builtin_amdgcn_mfma_f32_16x16x32_bf16(a, b, acc[n], 0, 0, 0);
        }
    }
    // D layout: col = lane&15, row = (lane>>4)*4 + reg   [m89 verified]
    int dcol = lane & 15;
    int dr0 = (lane >> 4) * 4;
#pragma unroll
    for (int n = 0; n < 4; n++) {
        int col = col0 + n * 16 + dcol;
        unsigned short* dst = (col < 512) ? h : g;
        int cc = col & 511;
#pragma unroll
        for (int r = 0; r < 4; r++) {
            int m = row0 + dr0 + r;
            dst[(size_t)m * 512 + cc] = f2bf(acc[n][r]);
        }
    }
}

// ---------------- kernel 5: s_left / s_right ----------------
__global__ void k_slr(const unsigned short* __restrict__ h, const float* __restrict__ a_sa,
                      float* __restrict__ sl, float* __restrict__ sr) {
    int wave = threadIdx.x >> 6, lane = threadIdx.x & 63;
    int row = blockIdx.x * 4 + wave;
    int k0 = lane * 8;
    uint4 hv = *(const uint4*)(h + (size_t)row * DD + k0);
    unsigned u[4] = {hv.x, hv.y, hv.z, hv.w};
    float s0 = 0, s1 = 0;
#pragma unroll
    for (int j = 0; j < 4; j++) {
        float h0 = bf2f((unsigned short)(u[j] & 0xffff));
        float h1 = bf2f((unsigned short)(u[j] >> 16));
        s0 += h0 * a_sa[k0 + 2 * j] + h1 * a_sa[k0 + 2 * j + 1];
        s1 += h0 * a_sa[512 + k0 + 2 * j] + h1 * a_sa[512 + k0 + 2 * j + 1];
    }
#pragma unroll
    for (int off = 32; off; off >>= 1) { s0 += __shfl_down(s0, off); s1 += __shfl_down(s1, off); }
    if (lane == 0) { sl[row] = s0; sr[row] = s1; }
}

// ---------------- kernel 6: attention normalize + gathers + epilogue ----------------
__global__ __launch_bounds__(256) void k_final(
    const int* __restrict__ idxA, const int* __restrict__ cntA,
    const int* __restrict__ idxB, const int* __restrict__ cntB,
    const unsigned short* __restrict__ h, const unsigned short* __restrict__ g,
    const float* __restrict__ sl, const float* __restrict__ sr,
    const float* __restrict__ gateA, const float* __restrict__ gateB,
    const float* __restrict__ bias, float* __restrict__ out) {
    int i = blockIdx.x;
    int tid = threadIdx.x;
    __shared__ float w[CAP];
    __shared__ int ja[CAP], jb[CAP];
    __shared__ float s_denom;

    int cA = cntA[i], cB = cntB[i];
    if (tid < cA) {
        int j = idxA[(size_t)i * CAP + tid];
        ja[tid] = j;
        float s = sl[i] + sr[j];
        float lrelu = s > 0.f ? s : 0.01f * s;
        w[tid] = expf(-lrelu);
    }
    if (tid < cB) jb[tid] = idxB[(size_t)i * CAP + tid];
    __syncthreads();

    if (tid < 64) {
        float p = 0.f;
        for (int t = tid; t < cA; t += 64) p += w[t];
#pragma unroll
        for (int off = 32; off; off >>= 1) p += __shfl_down(p, off);
        if (tid == 0) s_denom = p;
    }
    __syncthreads();
    float inv = 1.f / (s_denom + 1e-5f);
    if (tid < cA) w[tid] *= inv;
    __syncthreads();

    float ga = gateA[i], gb = gateB[i];
    int d0 = tid * 2;
    float a0 = 0, a1 = 0, b0 = 0, b1 = 0;
    for (int t = 0; t < cA; t++) {
        unsigned hv = *(const unsigned*)(h + (size_t)ja[t] * 512 + d0);
        float wt_ = w[t];
        a0 += wt_ * bf2f((unsigned short)(hv & 0xffff));
        a1 += wt_ * bf2f((unsigned short)(hv >> 16));
    }
    for (int t = 0; t < cB; t++) {
        unsigned gv = *(const unsigned*)(g + (size_t)jb[t] * 512 + d0);
        b0 += bf2f((unsigned short)(gv & 0xffff));
        b1 += bf2f((unsigned short)(gv >> 16));
    }
    float z0 = ga * a0 + gb * (b0 + bias[d0]);
    float z1 = ga * a1 + gb * (b1 + bias[d0 + 1]);
    out[(size_t)i * 512 + d0]     = sigmoidf_(z0);
    out[(size_t)i * 512 + d0 + 1] = sigmoidf_(z1);
}

extern "C" void kernel_launch(void* const* d_in, const int* in_sizes, int n_in,
                              void* d_out, int out_size, void* d_ws, size_t ws_size,
                              hipStream_t stream) {
    const float* x    = (const float*)d_in[0];
    const float* adjA = (const float*)d_in[1];
    const float* adjB = (const float*)d_in[2];
    const float* Wsa  = (const float*)d_in[3];
    const float* a_sa = (const float*)d_in[4];
    const float* Wg   = (const float*)d_in[5];
    const float* bg   = (const float*)d_in[6];
    const float* Wa   = (const float*)d_in[7];
    const float* ba   = (const float*)d_in[8];
    const float* Wb   = (const float*)d_in[9];
    const float* bb   = (const float*)d_in[10];
    float* out = (float*)d_out;

    char* ws = (char*)d_ws;
    size_t off = 0;
    auto alloc = [&](size_t bytes) -> void* {
        void* p = ws + off;
        off += (bytes + 255) & ~(size_t)255;
        return p;
    };
    unsigned short* xb = (unsigned short*)alloc((size_t)NN * DD * 2);   // x in bf16
    unsigned short* wt = (unsigned short*)alloc((size_t)1024 * DD * 2); // [W_sa|W_g]^T bf16
    unsigned short* h  = (unsigned short*)alloc((size_t)NN * DD * 2);   // x @ W_sa (bf16)
    unsigned short* g  = (unsigned short*)alloc((size_t)NN * DD * 2);   // x @ W_gcnb (bf16)
    int* idxA = (int*)alloc((size_t)NN * CAP * 4);
    int* idxB = (int*)alloc((size_t)NN * CAP * 4);
    int* cntA = (int*)alloc((size_t)NN * 4);
    int* cntB = (int*)alloc((size_t)NN * 4);
    float* xal = (float*)alloc((size_t)NN * 4);
    float* xar = (float*)alloc((size_t)NN * 4);
    float* xbl = (float*)alloc((size_t)NN * 4);
    float* xbr = (float*)alloc((size_t)NN * 4);
    float* gateA = (float*)alloc((size_t)NN * 4);
    float* gateB = (float*)alloc((size_t)NN * 4);
    float* sl = (float*)alloc((size_t)NN * 4);
    float* sr = (float*)alloc((size_t)NN * 4);

    // 1. dtype conversions
    k_conv_x<<<(NN * DD) / 4 / 256, 256, 0, stream>>>(x, xb);
    k_conv_w<<<(1024 * DD) / 256, 256, 0, stream>>>(Wsa, Wg, wt);
    // 2. gate projections
    k_proj<<<NN / 4, 256, 0, stream>>>(x, Wa, Wb, xal, xar, xbl, xbr);
    // 3. sparsify both adjacencies + gates
    k_sparsify<<<dim3(NN, 2), 256, 0, stream>>>(adjA, adjB, xal, xar, xbl, xbr, ba, bb,
                                                idxA, idxB, cntA, cntB, gateA, gateB);
    // 4. fused GEMM -> h, g
    k_gemm<<<dim3(NN / 64, 1024 / 64), 256, 0, stream>>>((const bf16_t*)xb, (const bf16_t*)wt, h, g);
    // 5. s_left / s_right
    k_slr<<<NN / 4, 256, 0, stream>>>(h, a_sa, sl, sr);
    // 6. attention + GCN gather + sigmoid epilogue
    k_final<<<NN, 256, 0, stream>>>(idxA, cntA, idxB, cntB, h, g, sl, sr, gateA, gateB, bg, out);
}

// Round 2
// 172.273 us; speedup vs baseline: 1.1199x; 1.1199x over previous
//
#include <hip/hip_runtime.h>
#include <math.h>

#define NN 6144
#define DD 512
#define CAP 128          // per-row index capacity (4 waves x 32)
#define WCAP 32          // per-wave capacity (mean nnz/wave ~7.7, 32 = +8.8 sigma)

typedef __bf16 bf16_t;
typedef __bf16 bf16x8 __attribute__((ext_vector_type(8)));
typedef unsigned short u16x8 __attribute__((ext_vector_type(8)));
typedef float f32x4 __attribute__((ext_vector_type(4)));

__device__ __forceinline__ float bf2f(unsigned short u) {
    unsigned v = ((unsigned)u) << 16;
    return __builtin_bit_cast(float, v);
}
__device__ __forceinline__ unsigned short f2bf(float f) {
    unsigned u = __builtin_bit_cast(unsigned, f);
    u += 0x7fffu + ((u >> 16) & 1u);   // round-to-nearest-even
    return (unsigned short)(u >> 16);
}
__device__ __forceinline__ float sigmoidf_(float z) { return 1.0f / (1.0f + expf(-z)); }

// ================= kernel P: W transpose->bf16  +  gate projections =================
// blocks [0,128): transpose [Wsa|Wg] (f32 [k][n]) -> wt (bf16 [n][k]) via LDS tiles
// blocks [128,1664): per-row gate projections x.Wa_l, x.Wa_r, x.Wb_l, x.Wb_r
__global__ __launch_bounds__(256) void k_prep(const float* __restrict__ Wsa,
                                              const float* __restrict__ Wg,
                                              const float* __restrict__ x,
                                              const float* __restrict__ Wa,
                                              const float* __restrict__ Wb,
                                              unsigned short* __restrict__ wt,
                                              float* __restrict__ xal, float* __restrict__ xar,
                                              float* __restrict__ xbl, float* __restrict__ xbr) {
    __shared__ float s[64][65];
    int bid = blockIdx.x;
    if (bid < 128) {
        // 64(n) x 64(k) tile; 16 tiles along n, 8 along k
        int n0 = (bid & 15) * 64;
        int k0 = (bid >> 4) * 64;
        int tx = threadIdx.x & 63, ty = threadIdx.x >> 6;
        const float* src = (n0 < 512) ? Wsa : Wg;
        int nn0 = n0 & 511;
#pragma unroll
        for (int kk = 0; kk < 64; kk += 4)
            s[kk + ty][tx] = src[(size_t)(k0 + kk + ty) * 512 + nn0 + tx];
        __syncthreads();
#pragma unroll
        for (int nn = 0; nn < 64; nn += 4)
            wt[(size_t)(n0 + nn + ty) * 512 + k0 + tx] = f2bf(s[tx][nn + ty]);
    } else {
        int wave = threadIdx.x >> 6, lane = threadIdx.x & 63;
        int row = (bid - 128) * 4 + wave;
        int k0 = lane * 8;
        const float* xr_ = x + (size_t)row * DD + k0;
        float4 v0 = *(const float4*)xr_;
        float4 v1 = *(const float4*)(xr_ + 4);
        float xv[8] = {v0.x, v0.y, v0.z, v0.w, v1.x, v1.y, v1.z, v1.w};
        float a0 = 0, a1 = 0, b0 = 0, b1 = 0;
#pragma unroll
        for (int j = 0; j < 8; j++) {
            a0 += xv[j] * Wa[k0 + j];
            a1 += xv[j] * Wa[512 + k0 + j];
            b0 += xv[j] * Wb[k0 + j];
            b1 += xv[j] * Wb[512 + k0 + j];
        }
#pragma unroll
        for (int off = 32; off; off >>= 1) {
            a0 += __shfl_down(a0, off); a1 += __shfl_down(a1, off);
            b0 += __shfl_down(b0, off); b1 += __shfl_down(b1, off);
        }
        if (lane == 0) { xal[row] = a0; xar[row] = a1; xbl[row] = b0; xbr[row] = b1; }
    }
}

// ================= kernel S: fused {sparsify A, sparsify B, GEMM} =================
// blocks [0, 12288): sparsify (one adjacency row per block; ballot compaction)
// blocks [12288, 13824): bf16 MFMA GEMM  [h|g] = x @ [W_sa|W_gcnb]
__global__ __launch_bounds__(256) void k_big(const float* __restrict__ x,
                                             const bf16_t* __restrict__ wt,
                                             const float* __restrict__ adjA,
                                             const float* __restrict__ adjB,
                                             int* __restrict__ idxA, int* __restrict__ idxB,
                                             int* __restrict__ cntA, int* __restrict__ cntB,
                                             unsigned short* __restrict__ h,
                                             unsigned short* __restrict__ g) {
    int bid = blockIdx.x;
    int wave = threadIdx.x >> 6, lane = threadIdx.x & 63;
    if (bid < 2 * NN) {
        int which = bid >= NN;
        int row = which ? bid - NN : bid;
        const float* adj = which ? adjB : adjA;
        int* idx = (which ? idxB : idxA) + (size_t)row * CAP;

        // preload: wave covers float4 indices [wave*384 + j*64 + lane], j=0..5
        const float4* arow = (const float4*)(adj + (size_t)row * NN);
        int base_i = wave * 384 + lane;
        float4 v[6];
#pragma unroll
        for (int j = 0; j < 6; j++) v[j] = arow[base_i + (size_t)j * 64];

        __shared__ int s_ent[4][WCAP];
        __shared__ int s_lc[4];
        unsigned long long below = (1ull << lane) - 1ull;
        int cnt = 0;
#pragma unroll
        for (int j = 0; j < 6; j++) {
            float f[4] = {v[j].x, v[j].y, v[j].z, v[j].w};
#pragma unroll
            for (int c = 0; c < 4; c++) {
                bool nz = (f[c] != 0.0f);
                unsigned long long m = __ballot(nz);
                if (nz) {
                    int pos = cnt + (int)__popcll(m & below);
                    if (pos < WCAP) s_ent[wave][pos] = (base_i + j * 64) * 4 + c;
                }
                cnt += (int)__popcll(m);
            }
        }
        if (cnt > WCAP) cnt = WCAP;
        if (lane == 0) s_lc[wave] = cnt;
        __syncthreads();
        int l0 = s_lc[0], l1 = s_lc[1], l2 = s_lc[2], l3 = s_lc[3];
        int total = l0 + l1 + l2 + l3;
        int t = threadIdx.x;
        if (t < total) {
            int w, o;
            if (t < l0) { w = 0; o = t; }
            else if (t < l0 + l1) { w = 1; o = t - l0; }
            else if (t < l0 + l1 + l2) { w = 2; o = t - l0 - l1; }
            else { w = 3; o = t - l0 - l1 - l2; }
            idx[t] = s_ent[w][o];
        }
        if (threadIdx.x == 0) (which ? cntB : cntA)[row] = total;
    } else {
        // ---- GEMM tile: 64 rows x 64 cols, 4 waves, MFMA 16x16x32 ----
        int tt = bid - 2 * NN;
        int row0 = (tt % (NN / 64)) * 64 + wave * 16;
        int col0 = (tt / (NN / 64)) * 64;
        int lr = lane & 15;
        int kg = (lane >> 4) * 8;

        f32x4 acc[4] = {{0,0,0,0},{0,0,0,0},{0,0,0,0},{0,0,0,0}};
        const float* ap = x + (size_t)(row0 + lr) * DD + kg;
        const bf16_t* bp = wt + (size_t)(col0 + lr) * DD + kg;

        for (int k0 = 0; k0 < DD; k0 += 32) {
            float4 a0 = *(const float4*)(ap + k0);
            float4 a1 = *(const float4*)(ap + k0 + 4);
            u16x8 au;
            au[0] = f2bf(a0.x); au[1] = f2bf(a0.y); au[2] = f2bf(a0.z); au[3] = f2bf(a0.w);
            au[4] = f2bf(a1.x); au[5] = f2bf(a1.y); au[6] = f2bf(a1.z); au[7] = f2bf(a1.w);
            bf16x8 a = __builtin_bit_cast(bf16x8, au);
#pragma unroll
            for (int n = 0; n < 4; n++) {
                bf16x8 b = *(const bf16x8*)(bp + (size_t)n * 16 * DD + k0);
                acc[n] = __builtin_amdgcn_mfma_f32_16x16x32_bf16(a, b, acc[n], 0, 0, 0);
            }
        }
        int dcol = lane & 15;
        int dr0 = (lane >> 4) * 4;
#pragma unroll
        for (int n = 0; n < 4; n++) {
            int col = col0 + n * 16 + dcol;
            unsigned short* dst = (col < 512) ? h : g;
            int cc = col & 511;
#pragma unroll
            for (int r = 0; r < 4; r++) {
                int m = row0 + dr0 + r;
                dst[(size_t)m * 512 + cc] = f2bf(acc[n][r]);
            }
        }
    }
}

// ================= kernel G: fused {gates from compacted lists, s_left/right} =================
// blocks [0,3072): gates — one (row,which) per wave
// blocks [3072,4608): s_left/s_right — one row per wave
__global__ __launch_bounds__(256) void k_gsl(const int* __restrict__ idxA, const int* __restrict__ cntA,
                                             const int* __restrict__ idxB, const int* __restrict__ cntB,
                                             const float* __restrict__ xal, const float* __restrict__ xar,
                                             const float* __restrict__ xbl, const float* __restrict__ xbr,
                                             const float* __restrict__ ba, const float* __restrict__ bb,
                                             const unsigned short* __restrict__ h,
                                             const float* __restrict__ a_sa,
                                             float* __restrict__ gateA, float* __restrict__ gateB,
                                             float* __restrict__ sl, float* __restrict__ sr) {
    int bid = blockIdx.x;
    int wave = threadIdx.x >> 6, lane = threadIdx.x & 63;
    if (bid < 3072) {
        int gw = bid * 4 + wave;          // 0..12287
        int row = gw >> 1;
        int which = gw & 1;
        int cnt = (which ? cntB : cntA)[row];
        const int* idx = (which ? idxB : idxA) + (size_t)row * CAP;
        const float* xl = which ? xbl : xal;
        float s = 0.f;
        for (int t = lane; t < cnt; t += 64) s += xl[idx[t]];
#pragma unroll
        for (int off = 32; off; off >>= 1) s += __shfl_down(s, off);
        if (lane == 0) {
            float z = s + (which ? xbr : xar)[row] + (which ? bb : ba)[0];
            (which ? gateB : gateA)[row] = sigmoidf_(z);
        }
    } else {
        int row = (bid - 3072) * 4 + wave;
        int k0 = lane * 8;
        uint4 hv = *(const uint4*)(h + (size_t)row * DD + k0);
        unsigned u[4] = {hv.x, hv.y, hv.z, hv.w};
        float s0 = 0, s1 = 0;
#pragma unroll
        for (int j = 0; j < 4; j++) {
            float h0 = bf2f((unsigned short)(u[j] & 0xffff));
            float h1 = bf2f((unsigned short)(u[j] >> 16));
            s0 += h0 * a_sa[k0 + 2 * j] + h1 * a_sa[k0 + 2 * j + 1];
            s1 += h0 * a_sa[512 + k0 + 2 * j] + h1 * a_sa[512 + k0 + 2 * j + 1];
        }
#pragma unroll
        for (int off = 32; off; off >>= 1) { s0 += __shfl_down(s0, off); s1 += __shfl_down(s1, off); }
        if (lane == 0) { sl[row] = s0; sr[row] = s1; }
    }
}

// ================= kernel F: attention normalize + gathers + epilogue =================
__global__ __launch_bounds__(256) void k_final(
    const int* __restrict__ idxA, const int* __restrict__ cntA,
    const int* __restrict__ idxB, const int* __restrict__ cntB,
    const unsigned short* __restrict__ h, const unsigned short* __restrict__ g,
    const float* __restrict__ sl, const float* __restrict__ sr,
    const float* __restrict__ gateA, const float* __restrict__ gateB,
    const float* __restrict__ bias, float* __restrict__ out) {
    int i = blockIdx.x;
    int tid = threadIdx.x;
    __shared__ float w[CAP];
    __shared__ int ja[CAP], jb[CAP];
    __shared__ float s_denom;

    int cA = cntA[i], cB = cntB[i];
    if (tid < cA) {
        int j = idxA[(size_t)i * CAP + tid];
        ja[tid] = j;
        float s = sl[i] + sr[j];
        float lrelu = s > 0.f ? s : 0.01f * s;
        w[tid] = expf(-lrelu);
    }
    if (tid < cB) jb[tid] = idxB[(size_t)i * CAP + tid];
    __syncthreads();

    if (tid < 64) {
        float p = 0.f;
        for (int t = tid; t < cA; t += 64) p += w[t];
#pragma unroll
        for (int off = 32; off; off >>= 1) p += __shfl_down(p, off);
        if (tid == 0) s_denom = p;
    }
    __syncthreads();
    float inv = 1.f / (s_denom + 1e-5f);
    if (tid < cA) w[tid] *= inv;
    __syncthreads();

    float ga = gateA[i], gb = gateB[i];
    int d0 = tid * 2;
    float a0 = 0, a1 = 0, b0 = 0, b1 = 0;
#pragma unroll 4
    for (int t = 0; t < cA; t++) {
        unsigned hv = *(const unsigned*)(h + (size_t)ja[t] * 512 + d0);
        float wt_ = w[t];
        a0 += wt_ * bf2f((unsigned short)(hv & 0xffff));
        a1 += wt_ * bf2f((unsigned short)(hv >> 16));
    }
#pragma unroll 4
    for (int t = 0; t < cB; t++) {
        unsigned gv = *(const unsigned*)(g + (size_t)jb[t] * 512 + d0);
        b0 += bf2f((unsigned short)(gv & 0xffff));
        b1 += bf2f((unsigned short)(gv >> 16));
    }
    float z0 = ga * a0 + gb * (b0 + bias[d0]);
    float z1 = ga * a1 + gb * (b1 + bias[d0 + 1]);
    out[(size_t)i * 512 + d0]     = sigmoidf_(z0);
    out[(size_t)i * 512 + d0 + 1] = sigmoidf_(z1);
}

extern "C" void kernel_launch(void* const* d_in, const int* in_sizes, int n_in,
                              void* d_out, int out_size, void* d_ws, size_t ws_size,
                              hipStream_t stream) {
    const float* x    = (const float*)d_in[0];
    const float* adjA = (const float*)d_in[1];
    const float* adjB = (const float*)d_in[2];
    const float* Wsa  = (const float*)d_in[3];
    const float* a_sa = (const float*)d_in[4];
    const float* Wg   = (const float*)d_in[5];
    const float* bg   = (const float*)d_in[6];
    const float* Wa   = (const float*)d_in[7];
    const float* ba   = (const float*)d_in[8];
    const float* Wb   = (const float*)d_in[9];
    const float* bb   = (const float*)d_in[10];
    float* out = (float*)d_out;

    char* ws = (char*)d_ws;
    size_t off = 0;
    auto alloc = [&](size_t bytes) -> void* {
        void* p = ws + off;
        off += (bytes + 255) & ~(size_t)255;
        return p;
    };
    unsigned short* wt = (unsigned short*)alloc((size_t)1024 * DD * 2); // [W_sa|W_g]^T bf16
    unsigned short* h  = (unsigned short*)alloc((size_t)NN * DD * 2);   // x @ W_sa (bf16)
    unsigned short* g  = (unsigned short*)alloc((size_t)NN * DD * 2);   // x @ W_gcnb (bf16)
    int* idxA = (int*)alloc((size_t)NN * CAP * 4);
    int* idxB = (int*)alloc((size_t)NN * CAP * 4);
    int* cntA = (int*)alloc((size_t)NN * 4);
    int* cntB = (int*)alloc((size_t)NN * 4);
    float* xal = (float*)alloc((size_t)NN * 4);
    float* xar = (float*)alloc((size_t)NN * 4);
    float* xbl = (float*)alloc((size_t)NN * 4);
    float* xbr = (float*)alloc((size_t)NN * 4);
    float* gateA = (float*)alloc((size_t)NN * 4);
    float* gateB = (float*)alloc((size_t)NN * 4);
    float* sl = (float*)alloc((size_t)NN * 4);
    float* sr = (float*)alloc((size_t)NN * 4);

    // P: W transpose + gate projections
    k_prep<<<128 + NN / 4, 256, 0, stream>>>(Wsa, Wg, x, Wa, Wb, wt, xal, xar, xbl, xbr);
    // S: sparsify A+B (streaming, ballot-compacted) fused with MFMA GEMM
    k_big<<<2 * NN + (NN / 64) * (1024 / 64), 256, 0, stream>>>(
        x, (const bf16_t*)wt, adjA, adjB, idxA, idxB, cntA, cntB, h, g);
    // G: gates from compacted lists + s_left/right
    k_gsl<<<3072 + NN / 4, 256, 0, stream>>>(idxA, cntA, idxB, cntB, xal, xar, xbl, xbr,
                                             ba, bb, h, a_sa, gateA, gateB, sl, sr);
    // F: attention + GCN gather + sigmoid epilogue
    k_final<<<NN, 256, 0, stream>>>(idxA, cntA, idxB, cntB, h, g, sl, sr, gateA, gateB, bg, out);
}

// Round 3
// 168.360 us; speedup vs baseline: 1.1460x; 1.0232x over previous
//
#include <hip/hip_runtime.h>
#include <math.h>

#define NN 6144
#define DD 512
#define CAP 128

typedef __bf16 bf16_t;
typedef __bf16 bf16x8 __attribute__((ext_vector_type(8)));
typedef unsigned short u16x8 __attribute__((ext_vector_type(8)));
typedef float f32x4 __attribute__((ext_vector_type(4)));

__device__ __forceinline__ float bf2f(unsigned short u) {
    unsigned v = ((unsigned)u) << 16;
    return __builtin_bit_cast(float, v);
}
__device__ __forceinline__ unsigned short f2bf(float f) {
    unsigned u = __builtin_bit_cast(unsigned, f);
    u += 0x7fffu + ((u >> 16) & 1u);   // round-to-nearest-even
    return (unsigned short)(u >> 16);
}
__device__ __forceinline__ float sigmoidf_(float z) { return 1.0f / (1.0f + expf(-z)); }

// ================= kernel P: W transpose->bf16  +  gate projections =================
__global__ __launch_bounds__(256) void k_prep(const float* __restrict__ Wsa,
                                              const float* __restrict__ Wg,
                                              const float* __restrict__ x,
                                              const float* __restrict__ Wa,
                                              const float* __restrict__ Wb,
                                              unsigned short* __restrict__ wt,
                                              float* __restrict__ xal, float* __restrict__ xar,
                                              float* __restrict__ xbl, float* __restrict__ xbr) {
    __shared__ float s[64][65];
    int bid = blockIdx.x;
    if (bid < 128) {
        int n0 = (bid & 15) * 64;
        int k0 = (bid >> 4) * 64;
        int tx = threadIdx.x & 63, ty = threadIdx.x >> 6;
        const float* src = (n0 < 512) ? Wsa : Wg;
        int nn0 = n0 & 511;
#pragma unroll
        for (int kk = 0; kk < 64; kk += 4)
            s[kk + ty][tx] = src[(size_t)(k0 + kk + ty) * 512 + nn0 + tx];
        __syncthreads();
#pragma unroll
        for (int nn = 0; nn < 64; nn += 4)
            wt[(size_t)(n0 + nn + ty) * 512 + k0 + tx] = f2bf(s[tx][nn + ty]);
    } else {
        int wave = threadIdx.x >> 6, lane = threadIdx.x & 63;
        int row = (bid - 128) * 4 + wave;
        int k0 = lane * 8;
        const float* xr_ = x + (size_t)row * DD + k0;
        float4 v0 = *(const float4*)xr_;
        float4 v1 = *(const float4*)(xr_ + 4);
        float xv[8] = {v0.x, v0.y, v0.z, v0.w, v1.x, v1.y, v1.z, v1.w};
        float a0 = 0, a1 = 0, b0 = 0, b1 = 0;
#pragma unroll
        for (int j = 0; j < 8; j++) {
            a0 += xv[j] * Wa[k0 + j];
            a1 += xv[j] * Wa[512 + k0 + j];
            b0 += xv[j] * Wb[k0 + j];
            b1 += xv[j] * Wb[512 + k0 + j];
        }
#pragma unroll
        for (int off = 32; off; off >>= 1) {
            a0 += __shfl_down(a0, off); a1 += __shfl_down(a1, off);
            b0 += __shfl_down(b0, off); b1 += __shfl_down(b1, off);
        }
        if (lane == 0) { xal[row] = a0; xar[row] = a1; xbl[row] = b0; xbr[row] = b1; }
    }
}

// ================= kernel FUSED: {row-scan sparsify (per-wave)} interleaved with {MFMA GEMM} =====
// 4608 blocks of 256. bid%3 in {0,1} -> scan block (4 waves x 1 row);  bid%3==2 -> GEMM tile.
__global__ __launch_bounds__(256) void k_fused(const float* __restrict__ x,
                                               const bf16_t* __restrict__ wt,
                                               const float* __restrict__ adjA,
                                               const float* __restrict__ adjB,
                                               int* __restrict__ idxA, int* __restrict__ idxB,
                                               int* __restrict__ cntA, int* __restrict__ cntB,
                                               unsigned short* __restrict__ h,
                                               unsigned short* __restrict__ g) {
    int bid = blockIdx.x;
    int wave = threadIdx.x >> 6, lane = threadIdx.x & 63;
    int grp = bid % 3;
    if (grp < 2) {
        // ---------- scan: one wave = one adjacency row, 24 loads in flight, no LDS/barriers ----
        int sid = (bid / 3) * 2 + grp;          // 0..3071
        int row = sid * 4 + wave;               // 0..12287
        int which = row >= NN;
        int r = which ? row - NN : row;
        const float* adj = which ? adjB : adjA;
        int* idx = (which ? idxB : idxA) + (size_t)r * CAP;
        int* cnt = which ? cntB : cntA;

        const float4* arow = (const float4*)(adj + (size_t)r * NN) + lane;
        float4 v[24];
#pragma unroll
        for (int j = 0; j < 24; j++) v[j] = arow[j * 64];

        unsigned m[3] = {0, 0, 0};
#pragma unroll
        for (int j = 0; j < 24; j++) {
            unsigned w_ = (j >> 3);
            unsigned sh = (j & 7) * 4;
            m[w_] |= (v[j].x != 0.f ? 1u : 0u) << sh;
            m[w_] |= (v[j].y != 0.f ? 1u : 0u) << (sh + 1);
            m[w_] |= (v[j].z != 0.f ? 1u : 0u) << (sh + 2);
            m[w_] |= (v[j].w != 0.f ? 1u : 0u) << (sh + 3);
        }
        int c = __popc(m[0]) + __popc(m[1]) + __popc(m[2]);
        // inclusive prefix-sum across 64 lanes
        int p = c;
#pragma unroll
        for (int off = 1; off < 64; off <<= 1) {
            int t = __shfl_up(p, off);
            if (lane >= off) p += t;
        }
        int pos = p - c;                 // exclusive prefix
        int total = __shfl(p, 63);
        // extract set bits -> column indices -> global scatter
#pragma unroll
        for (int w_ = 0; w_ < 3; w_++) {
            unsigned mm = m[w_];
            while (mm) {
                int b = __ffs(mm) - 1;
                mm &= mm - 1;
                int e = w_ * 32 + b;               // element 0..95 within lane
                int col = (e >> 2) * 256 + lane * 4 + (e & 3);
                if (pos < CAP) idx[pos] = col;
                pos++;
            }
        }
        if (lane == 0) cnt[r] = total > CAP ? CAP : total;
    } else {
        // ---------- GEMM tile: 64 rows x 64 cols, MFMA 16x16x32, A cvt in-register ----------
        int tt = bid / 3;                        // 0..1535
        int row0 = (tt % (NN / 64)) * 64 + wave * 16;
        int col0 = (tt / (NN / 64)) * 64;
        int lr = lane & 15;
        int kg = (lane >> 4) * 8;

        f32x4 acc[4] = {{0,0,0,0},{0,0,0,0},{0,0,0,0},{0,0,0,0}};
        const float* ap = x + (size_t)(row0 + lr) * DD + kg;
        const bf16_t* bp = wt + (size_t)(col0 + lr) * DD + kg;

        for (int k0 = 0; k0 < DD; k0 += 32) {
            float4 a0 = *(const float4*)(ap + k0);
            float4 a1 = *(const float4*)(ap + k0 + 4);
            u16x8 au;
            au[0] = f2bf(a0.x); au[1] = f2bf(a0.y); au[2] = f2bf(a0.z); au[3] = f2bf(a0.w);
            au[4] = f2bf(a1.x); au[5] = f2bf(a1.y); au[6] = f2bf(a1.z); au[7] = f2bf(a1.w);
            bf16x8 a = __builtin_bit_cast(bf16x8, au);
#pragma unroll
            for (int n = 0; n < 4; n++) {
                bf16x8 b = *(const bf16x8*)(bp + (size_t)n * 16 * DD + k0);
                acc[n] = __builtin_amdgcn_mfma_f32_16x16x32_bf16(a, b, acc[n], 0, 0, 0);
            }
        }
        int dcol = lane & 15;
        int dr0 = (lane >> 4) * 4;
#pragma unroll
        for (int n = 0; n < 4; n++) {
            int col = col0 + n * 16 + dcol;
            unsigned short* dst = (col < 512) ? h : g;
            int cc = col & 511;
#pragma unroll
            for (int r = 0; r < 4; r++) {
                int mr = row0 + dr0 + r;
                dst[(size_t)mr * 512 + cc] = f2bf(acc[n][r]);
            }
        }
    }
}

// ================= kernel SLR: s_left / s_right (one row per wave) =================
__global__ __launch_bounds__(256) void k_slr(const unsigned short* __restrict__ h,
                                             const float* __restrict__ a_sa,
                                             float* __restrict__ sl, float* __restrict__ sr) {
    int wave = threadIdx.x >> 6, lane = threadIdx.x & 63;
    int row = blockIdx.x * 4 + wave;
    int k0 = lane * 8;
    uint4 hv = *(const uint4*)(h + (size_t)row * DD + k0);
    unsigned u[4] = {hv.x, hv.y, hv.z, hv.w};
    float s0 = 0, s1 = 0;
#pragma unroll
    for (int j = 0; j < 4; j++) {
        float h0 = bf2f((unsigned short)(u[j] & 0xffff));
        float h1 = bf2f((unsigned short)(u[j] >> 16));
        s0 += h0 * a_sa[k0 + 2 * j] + h1 * a_sa[k0 + 2 * j + 1];
        s1 += h0 * a_sa[512 + k0 + 2 * j] + h1 * a_sa[512 + k0 + 2 * j + 1];
    }
#pragma unroll
    for (int off = 32; off; off >>= 1) { s0 += __shfl_down(s0, off); s1 += __shfl_down(s1, off); }
    if (lane == 0) { sl[row] = s0; sr[row] = s1; }
}

// ================= kernel F: gates + attention normalize + gathers + epilogue =================
__global__ __launch_bounds__(256) void k_final(
    const int* __restrict__ idxA, const int* __restrict__ cntA,
    const int* __restrict__ idxB, const int* __restrict__ cntB,
    const unsigned short* __restrict__ h, const unsigned short* __restrict__ g,
    const float* __restrict__ sl, const float* __restrict__ sr,
    const float* __restrict__ xal, const float* __restrict__ xar,
    const float* __restrict__ xbl, const float* __restrict__ xbr,
    const float* __restrict__ ba, const float* __restrict__ bb,
    const float* __restrict__ bias, float* __restrict__ out) {
    int i = blockIdx.x;
    int tid = threadIdx.x;
    __shared__ float w[CAP];
    __shared__ int ja[CAP], jb[CAP];
    __shared__ float s_denom, s_ga, s_gb;

    int cA = cntA[i], cB = cntB[i];
    if (tid < cA) {
        int j = idxA[(size_t)i * CAP + tid];
        ja[tid] = j;
        float s = sl[i] + sr[j];
        float lrelu = s > 0.f ? s : 0.01f * s;
        w[tid] = expf(-lrelu);
    }
    if (tid < cB) jb[tid] = idxB[(size_t)i * CAP + tid];
    __syncthreads();

    if (tid < 64) {
        float p = 0.f, gasum = 0.f, gbsum = 0.f;
        for (int t = tid; t < cA; t += 64) { p += w[t]; gasum += xal[ja[t]]; }
        for (int t = tid; t < cB; t += 64) gbsum += xbl[jb[t]];
#pragma unroll
        for (int off = 32; off; off >>= 1) {
            p += __shfl_down(p, off);
            gasum += __shfl_down(gasum, off);
            gbsum += __shfl_down(gbsum, off);
        }
        if (tid == 0) {
            s_denom = p;
            s_ga = sigmoidf_(gasum + xar[i] + ba[0]);
            s_gb = sigmoidf_(gbsum + xbr[i] + bb[0]);
        }
    }
    __syncthreads();
    float inv = 1.f / (s_denom + 1e-5f);
    float ga = s_ga, gb = s_gb;

    int d0 = tid * 2;
    float a0 = 0, a1 = 0, b0 = 0, b1 = 0;
#pragma unroll 4
    for (int t = 0; t < cA; t++) {
        unsigned hv = *(const unsigned*)(h + (size_t)ja[t] * 512 + d0);
        float wt_ = w[t];
        a0 += wt_ * bf2f((unsigned short)(hv & 0xffff));
        a1 += wt_ * bf2f((unsigned short)(hv >> 16));
    }
#pragma unroll 4
    for (int t = 0; t < cB; t++) {
        unsigned gv = *(const unsigned*)(g + (size_t)jb[t] * 512 + d0);
        b0 += bf2f((unsigned short)(gv & 0xffff));
        b1 += bf2f((unsigned short)(gv >> 16));
    }
    float z0 = ga * (a0 * inv) + gb * (b0 + bias[d0]);
    float z1 = ga * (a1 * inv) + gb * (b1 + bias[d0 + 1]);
    out[(size_t)i * 512 + d0]     = sigmoidf_(z0);
    out[(size_t)i * 512 + d0 + 1] = sigmoidf_(z1);
}

extern "C" void kernel_launch(void* const* d_in, const int* in_sizes, int n_in,
                              void* d_out, int out_size, void* d_ws, size_t ws_size,
                              hipStream_t stream) {
    const float* x    = (const float*)d_in[0];
    const float* adjA = (const float*)d_in[1];
    const float* adjB = (const float*)d_in[2];
    const float* Wsa  = (const float*)d_in[3];
    const float* a_sa = (const float*)d_in[4];
    const float* Wg   = (const float*)d_in[5];
    const float* bg   = (const float*)d_in[6];
    const float* Wa   = (const float*)d_in[7];
    const float* ba   = (const float*)d_in[8];
    const float* Wb   = (const float*)d_in[9];
    const float* bb   = (const float*)d_in[10];
    float* out = (float*)d_out;

    char* ws = (char*)d_ws;
    size_t off = 0;
    auto alloc = [&](size_t bytes) -> void* {
        void* p = ws + off;
        off += (bytes + 255) & ~(size_t)255;
        return p;
    };
    unsigned short* wt = (unsigned short*)alloc((size_t)1024 * DD * 2);
    unsigned short* h  = (unsigned short*)alloc((size_t)NN * DD * 2);
    unsigned short* g  = (unsigned short*)alloc((size_t)NN * DD * 2);
    int* idxA = (int*)alloc((size_t)NN * CAP * 4);
    int* idxB = (int*)alloc((size_t)NN * CAP * 4);
    int* cntA = (int*)alloc((size_t)NN * 4);
    int* cntB = (int*)alloc((size_t)NN * 4);
    float* xal = (float*)alloc((size_t)NN * 4);
    float* xar = (float*)alloc((size_t)NN * 4);
    float* xbl = (float*)alloc((size_t)NN * 4);
    float* xbr = (float*)alloc((size_t)NN * 4);
    float* sl = (float*)alloc((size_t)NN * 4);
    float* sr = (float*)alloc((size_t)NN * 4);

    // P: W transpose + gate projections
    k_prep<<<128 + NN / 4, 256, 0, stream>>>(Wsa, Wg, x, Wa, Wb, wt, xal, xar, xbl, xbr);
    // FUSED: per-wave row scan (deep MLP, no barriers) interleaved with MFMA GEMM
    k_fused<<<4608, 256, 0, stream>>>(x, (const bf16_t*)wt, adjA, adjB,
                                      idxA, idxB, cntA, cntB, h, g);
    // SLR: s_left / s_right
    k_slr<<<NN / 4, 256, 0, stream>>>(h, a_sa, sl, sr);
    // F: gates + attention + GCN gather + sigmoid epilogue
    k_final<<<NN, 256, 0, stream>>>(idxA, cntA, idxB, cntB, h, g, sl, sr,
                                    xal, xar, xbl, xbr, ba, bb, bg, out);
}